// Round 14
// baseline (130.112 us; speedup 1.0000x reference)
//
#include <hip/hip_runtime.h>
#include <math.h>

// ---------------------------------------------------------------------------
// EntRNN R18b: resubmit of R18 (Round 13 never acquired a GPU). R17 + two
// staging fixes (K-loop proven off-critical-path: R15/R16/R17 with radically
// different K-loops all measure 125-127us).
//  * A-stage coalescing: lane 8r+c now reads bytes c*32 + j*256 (contiguous
//    256B per 8-lane group per instruction; was c*128 + j*32 = 64 scattered
//    16B pieces). Same kcg set {0..31}, same xor-swizzle formula.
//  * Non-temporal: A loads (read-once globally, keep L2 for W/HP) and
//    final_k out stores (never re-read). HP keeps normal policy (L3 reuse).
// Base: CHUNK=32, 1024 blocks, 4 blocks/CU, barrier-free K-loop with W
// fragments direct from L2, scan_mid + streaming final_k tail.
// R15=125.2  R16=127.4  R17=127.2; ~47us of total is harness fill/memset.
// B=8, T=4096, D=256.
// ---------------------------------------------------------------------------

typedef _Float16 f16x8 __attribute__((ext_vector_type(8)));
typedef float f32x4 __attribute__((ext_vector_type(4)));
typedef float f32x16 __attribute__((ext_vector_type(16)));
typedef unsigned int u32x4 __attribute__((ext_vector_type(4)));

constexpr int B_ = 8, T_ = 4096, D_ = 256, K_ = 256;
constexpr int M_ = B_ * T_;          // 32768 rows
constexpr int CHUNK = 32;            // rows per gemm block == scan chunk
constexpr int NCH = T_ / CHUNK;      // 128 chunks per sequence
constexpr int NBLK = M_ / CHUNK;     // 1024 gemm blocks
constexpr int SLICE_EL = 8192;       // W slice stride in f16 elements

struct alignas(4) XF { _Float16 x, f; };
struct alignas(4) HP2 { _Float16 h, p; };
union UHP { unsigned int u; HP2 hp; XF xf; };

__device__ __forceinline__ float fexp2(float a) { return __builtin_amdgcn_exp2f(a); }
__device__ __forceinline__ float frcp(float a) { return __builtin_amdgcn_rcpf(a); }
constexpr float L2E = 1.4426950408889634f;

__device__ __forceinline__ float fast_sigmoid(float z) {
  return frcp(1.f + fexp2(-z * L2E));
}
__device__ __forceinline__ float fast_tanh(float z) {
  const float t = fexp2(-2.f * L2E * fabsf(z));
  return copysignf((1.f - t) * frcp(1.f + t), z);
}

// ---- K0: repack W fp32 -> f16. Chunk id t = kk2*1024 + (mat*2+kc)*256 + n,
// chunk = W[n][kk2*16 + kc*8 .. +8). 16384 chunks of 8 f16.
__global__ __launch_bounds__(256) void wconv(const float* __restrict__ Win,
                                             const float* __restrict__ Wf,
                                             _Float16* __restrict__ Wh2) {
  const int t = blockIdx.x * 256 + threadIdx.x;
  const int n = t & 255;
  const int kc = (t >> 8) & 1;
  const int mat = (t >> 9) & 1;
  const int kk2 = t >> 10;
  const float* s = (mat ? Wf : Win) + (size_t)n * K_ + kk2 * 16 + kc * 8;
  f32x4 a = *(const f32x4*)s;
  f32x4 b = *(const f32x4*)(s + 4);
  f16x8 o;
  o[0] = (_Float16)a[0]; o[1] = (_Float16)a[1];
  o[2] = (_Float16)a[2]; o[3] = (_Float16)a[3];
  o[4] = (_Float16)b[0]; o[5] = (_Float16)b[1];
  o[6] = (_Float16)b[2]; o[7] = (_Float16)b[3];
  *(f16x8*)(Wh2 + (size_t)t * 8) = o;
}

// ---- K1: GEMM (32-row tile, W direct from L2) + act + local scan -> HP ----
// 1024 blocks x 256 thr, 32 KiB LDS, launch_bounds(256,4) -> 4 blocks/CU.
// Wave w owns cols [w*64, w*64+64) of BOTH matrices. K-loop: 1 LDS read +
// 4 global fragment reads + 4 MFMA per iter, barrier-free.
__global__ __launch_bounds__(256, 4) void gemm_hp(
    const float* __restrict__ A, const _Float16* __restrict__ Wh2,
    const float* __restrict__ bin, const float* __restrict__ bfv,
    const float* __restrict__ mask, unsigned int* __restrict__ HPout,
    float* __restrict__ Ap, float* __restrict__ Hp) {
  __shared__ __align__(16) char smem[32768];
  char* ldsA = smem;            // 16 KiB: [m(32)][swz(32)] 16B, swz = kcg^m
  // epilogue: smem[0:32768) = 32 rows x 256 cols of XF/HP2 (4B each)

  const int tid = threadIdx.x;
  const int w = tid >> 6, lane = tid & 63;
  const int nl = lane & 31, kh = lane >> 5;
  const int g = blockIdx.x;
  const int row0 = g * CHUNK;

  f32x16 acc[2][2];
#pragma unroll
  for (int mat = 0; mat < 2; ++mat)
#pragma unroll
    for (int nt = 0; nt < 2; ++nt) acc[mat][nt] = (f32x16)(0.f);

  // ---- stage ALL of A (32 x 256) fp32->f16, xor-swizzled ----
  // Lane 8r+c reads bytes r*1024 + c*32 + j*256 (+16): contiguous 256B per
  // 8-lane group per instruction. kcg = j*8 + c covers 0..31 across j.
  {
    const int am = tid >> 3;                 // row 0..31 (8 thr/row)
    const float* agp = A + (size_t)(row0 + am) * K_ + (tid & 7) * 8;
#pragma unroll
    for (int j = 0; j < 4; ++j) {
      const int kcg = j * 8 + (tid & 7);
      f32x4 lo = __builtin_nontemporal_load((const f32x4*)(agp + j * 64));
      f32x4 hi = __builtin_nontemporal_load((const f32x4*)(agp + j * 64 + 4));
      f16x8 t;
      t[0] = (_Float16)lo[0]; t[1] = (_Float16)lo[1];
      t[2] = (_Float16)lo[2]; t[3] = (_Float16)lo[3];
      t[4] = (_Float16)hi[0]; t[5] = (_Float16)hi[1];
      t[6] = (_Float16)hi[2]; t[7] = (_Float16)hi[3];
      *(f16x8*)(ldsA + am * 512 + ((kcg ^ am) << 4)) = t;
    }
  }
  __syncthreads();   // ldsA visible to all waves (the ONLY pre-epilogue barrier)

  // ---- K-loop: 16 slices of K=16, W fragments direct from global/L2 ----
  {
    const _Float16* wfrag = Wh2 + (size_t)(kh * 256 + w * 64 + nl) * 8;
    for (int kk2 = 0; kk2 < 16; ++kk2) {
      f16x8 afr;
      {
        const int kcg = kk2 * 2 + kh;
        afr = *(const f16x8*)(ldsA + nl * 512 + ((kcg ^ nl) << 4));
      }
#pragma unroll
      for (int mat = 0; mat < 2; ++mat)
#pragma unroll
        for (int nt = 0; nt < 2; ++nt) {
          f16x8 bfr = *(const f16x8*)(wfrag + (size_t)(mat * 512 + nt * 32) * 8);
          acc[mat][nt] = __builtin_amdgcn_mfma_f32_32x32x16_f16(
              afr, bfr, acc[mat][nt], 0, 0, 0);
        }
      wfrag += SLICE_EL;
    }
  }
  __syncthreads();   // all waves done with ldsA before epilogue reuse

  // ---- epilogue: activations for all 32 rows into 32 KiB LDS ----
  float bx[2], bf[2];
#pragma unroll
  for (int nt = 0; nt < 2; ++nt) {
    const int col = w * 64 + nt * 32 + nl;
    bx[nt] = bin[col];
    bf[nt] = bfv[col];
  }
  float madd[16];
#pragma unroll
  for (int reg = 0; reg < 16; ++reg) {
    const int rl = (reg & 3) + 8 * (reg >> 2) + 4 * kh;   // 0..31
    madd[reg] = 10000.f * mask[row0 + rl];
  }

#pragma unroll
  for (int nt = 0; nt < 2; ++nt) {
    const int col = w * 64 + nt * 32 + nl;
#pragma unroll
    for (int reg = 0; reg < 16; ++reg) {
      const int rloc = (reg & 3) + 8 * (reg >> 2) + 4 * kh;  // 0..31
      const float zx = acc[0][nt][reg] + bx[nt];
      const float zf = acc[1][nt][reg] + bf[nt] + madd[reg];
      XF v;
      v.x = (_Float16)fast_tanh(zx);
      v.f = (_Float16)fast_sigmoid(zf);
      *(XF*)(smem + ((size_t)rloc * D_ + col) * 4) = v;
    }
  }
  __syncthreads();

  // ---- local scan: 32 timesteps in place (XF -> HP2) ----
  const int d = tid;
  float hrun = 0.f, Prun = 1.f;
#pragma unroll 8
  for (int t = 0; t < 32; ++t) {
    char* slot = smem + ((size_t)t * D_ + d) * 4;
    const XF v = *(const XF*)slot;
    const float f = (float)v.f;
    const float a = 1.f - f;
    hrun = f * (float)v.x + a * hrun;
    Prun *= a;
    HP2 o;
    o.h = (_Float16)hrun;
    o.p = (_Float16)Prun;
    *(HP2*)slot = o;
  }
  __syncthreads();

  // ---- bulk-coalesced b128 store of the 32-row HP stage (32 KiB) ----
#pragma unroll
  for (int j = 0; j < 8; ++j) {
    const int c = j * 256 + tid;              // 16B chunk id in [0,2048)
    u32x4 vv = *(const u32x4*)(smem + (size_t)c * 16);
    *(u32x4*)(HPout + (size_t)g * 8192 + (size_t)c * 4) = vv;
  }

  Ap[(size_t)g * D_ + d] = Prun;
  Hp[(size_t)g * D_ + d] = hrun;
}

// ---- K2: chunk carries, computed ONCE. 8 blocks x 256 thr ----------------
__global__ __launch_bounds__(256) void scan_mid(const float* __restrict__ Ap,
                                                const float* __restrict__ Hp,
                                                float* __restrict__ hs) {
  const int b = blockIdx.x, d = threadIdx.x;
  float h = 0.f;
#pragma unroll 8
  for (int c = 0; c < NCH; ++c) {
    const size_t i = ((size_t)(b * NCH + c)) * D_ + d;
    hs[i] = h;                         // carry INTO chunk c
    h = Hp[i] + Ap[i] * h;
  }
}

// ---- K3: h = h_local + P * h_start, pure streaming ------------------------
__global__ __launch_bounds__(256) void final_k(const unsigned int* __restrict__ HP,
                                               const float* __restrict__ hs,
                                               float* __restrict__ out) {
  const int g = blockIdx.x;
  const int wv = threadIdx.x >> 6;
  const int d0 = (threadIdx.x & 63) * 4;
  const f32x4 h0 = *(const f32x4*)(hs + (size_t)g * D_ + d0);
#pragma unroll 4
  for (int tt = 0; tt < 8; ++tt) {
    const int t = wv * 8 + tt;
    const size_t idx = ((size_t)g * CHUNK + t) * D_ + d0;
    u32x4 u = *(const u32x4*)(HP + idx);
    f32x4 o;
#pragma unroll
    for (int i = 0; i < 4; ++i) {
      UHP q; q.u = u[i];
      o[i] = (float)q.hp.h + (float)q.hp.p * h0[i];
    }
    __builtin_nontemporal_store(o, (f32x4*)(out + idx));
  }
}

// ---------------------------------------------------------------------------
extern "C" void kernel_launch(void* const* d_in, const int* in_sizes, int n_in,
                              void* d_out, int out_size, void* d_ws, size_t ws_size,
                              hipStream_t stream) {
  const float* inputs = (const float*)d_in[0];
  const float* mask   = (const float*)d_in[1];
  const float* W_in   = (const float*)d_in[2];
  const float* b_in   = (const float*)d_in[3];
  const float* W_f    = (const float*)d_in[4];
  const float* b_f    = (const float*)d_in[5];
  float* out = (float*)d_out;
  char* ws = (char*)d_ws;

  constexpr size_t HPSZ = (size_t)M_ * D_ * 4;                    // 32 MiB
  constexpr size_t WSZ  = (size_t)2 * 256 * 256 * 2;              // 256 KiB
  constexpr size_t SUM  = (size_t)NBLK * D_ * sizeof(float);      // 1 MiB

  unsigned int* HPb = (unsigned int*)ws;
  _Float16* Wh2 = (_Float16*)(ws + HPSZ);
  float* Ap = (float*)(ws + HPSZ + WSZ);
  float* Hp = (float*)(ws + HPSZ + WSZ + SUM);
  float* hs = (float*)(ws + HPSZ + WSZ + 2 * SUM);

  wconv<<<64, 256, 0, stream>>>(W_in, W_f, Wh2);
  gemm_hp<<<NBLK, 256, 0, stream>>>(inputs, Wh2, b_in, b_f, mask, HPb, Ap, Hp);
  scan_mid<<<B_, 256, 0, stream>>>(Ap, Hp, hs);
  final_k<<<NBLK, 256, 0, stream>>>(HPb, hs, out);
}

// Round 15
// 124.665 us; speedup vs baseline: 1.0437x; 1.0437x over previous
//
#include <hip/hip_runtime.h>
#include <math.h>

// ---------------------------------------------------------------------------
// EntRNN R19: occupancy push — the only lever that ever moved gemm_hp
// (R14: 8->16 waves/CU = 57->40us; R16/R17/R18 sync/LDS/staging variants all
// neutral). Same CHUNK=32 math re-sharded over 8 waves of a 512-thread
// block: wave w owns (mat = w>>2, 64-col group = w&3) -> acc = 2 x f32x16 =
// 32 regs/thread (was 64). ~75 unified regs -> launch_bounds(512,6) = 3
// blocks/CU = 24 waves/CU (was 16). Epilogue: x/f halves of each XF pair
// now written by different waves as disjoint 2B halves (no race; barrier
// before scan). Scan runs on threads 0..255. HP layout, scan_mid, final_k
// unchanged from R15 (best measured, 125.2us; ~47us is harness fill).
// B=8, T=4096, D=256.
// ---------------------------------------------------------------------------

typedef _Float16 f16x8 __attribute__((ext_vector_type(8)));
typedef float f32x4 __attribute__((ext_vector_type(4)));
typedef float f32x16 __attribute__((ext_vector_type(16)));
typedef unsigned int u32x4 __attribute__((ext_vector_type(4)));

constexpr int B_ = 8, T_ = 4096, D_ = 256, K_ = 256;
constexpr int M_ = B_ * T_;          // 32768 rows
constexpr int CHUNK = 32;            // rows per gemm block == scan chunk
constexpr int NCH = T_ / CHUNK;      // 128 chunks per sequence
constexpr int NBLK = M_ / CHUNK;     // 1024 gemm blocks
constexpr int SLICE_EL = 8192;       // W slice stride in f16 elements

struct alignas(4) XF { _Float16 x, f; };
struct alignas(4) HP2 { _Float16 h, p; };
union UHP { unsigned int u; HP2 hp; XF xf; };

__device__ __forceinline__ float fexp2(float a) { return __builtin_amdgcn_exp2f(a); }
__device__ __forceinline__ float frcp(float a) { return __builtin_amdgcn_rcpf(a); }
constexpr float L2E = 1.4426950408889634f;

__device__ __forceinline__ float fast_sigmoid(float z) {
  return frcp(1.f + fexp2(-z * L2E));
}
__device__ __forceinline__ float fast_tanh(float z) {
  const float t = fexp2(-2.f * L2E * fabsf(z));
  return copysignf((1.f - t) * frcp(1.f + t), z);
}

// ---- K0: repack W fp32 -> f16. Chunk id t = kk2*1024 + (mat*2+kc)*256 + n,
// chunk = W[n][kk2*16 + kc*8 .. +8). 16384 chunks of 8 f16.
__global__ __launch_bounds__(256) void wconv(const float* __restrict__ Win,
                                             const float* __restrict__ Wf,
                                             _Float16* __restrict__ Wh2) {
  const int t = blockIdx.x * 256 + threadIdx.x;
  const int n = t & 255;
  const int kc = (t >> 8) & 1;
  const int mat = (t >> 9) & 1;
  const int kk2 = t >> 10;
  const float* s = (mat ? Wf : Win) + (size_t)n * K_ + kk2 * 16 + kc * 8;
  f32x4 a = *(const f32x4*)s;
  f32x4 b = *(const f32x4*)(s + 4);
  f16x8 o;
  o[0] = (_Float16)a[0]; o[1] = (_Float16)a[1];
  o[2] = (_Float16)a[2]; o[3] = (_Float16)a[3];
  o[4] = (_Float16)b[0]; o[5] = (_Float16)b[1];
  o[6] = (_Float16)b[2]; o[7] = (_Float16)b[3];
  *(f16x8*)(Wh2 + (size_t)t * 8) = o;
}

// ---- K1: GEMM (32-row tile, 8 waves, W direct from L2) + act + scan -> HP -
// 1024 blocks x 512 thr, 32 KiB LDS, launch_bounds(512,6) -> 3 blocks/CU =
// 24 waves/CU. Wave w: mat = w>>2, col group cg = w&3 (64 cols), acc = 2 x
// f32x16. K-loop: 1 LDS read + 2 global fragment reads + 2 MFMA per iter,
// barrier-free.
__global__ __launch_bounds__(512, 6) void gemm_hp(
    const float* __restrict__ A, const _Float16* __restrict__ Wh2,
    const float* __restrict__ bin, const float* __restrict__ bfv,
    const float* __restrict__ mask, unsigned int* __restrict__ HPout,
    float* __restrict__ Ap, float* __restrict__ Hp) {
  __shared__ __align__(16) char smem[32768];
  char* ldsA = smem;            // 16 KiB: [m(32)][swz(32)] 16B, swz = kcg^m
  // epilogue: smem[0:32768) = 32 rows x 256 cols of XF/HP2 (4B each)

  const int tid = threadIdx.x;
  const int w = tid >> 6, lane = tid & 63;
  const int nl = lane & 31, kh = lane >> 5;
  const int mat = w >> 2, cg = w & 3;
  const int g = blockIdx.x;
  const int row0 = g * CHUNK;

  f32x16 acc[2];
  acc[0] = (f32x16)(0.f);
  acc[1] = (f32x16)(0.f);

  // ---- stage ALL of A (32 x 256) fp32->f16, xor-swizzled; 16 thr/row ----
  {
    const int am = tid >> 4;                 // row 0..31
    const float* agp = A + (size_t)(row0 + am) * K_ + (tid & 15) * 16;
#pragma unroll
    for (int j = 0; j < 2; ++j) {
      const int kcg = (tid & 15) * 2 + j;
      f32x4 lo = *(const f32x4*)(agp + j * 8);
      f32x4 hi = *(const f32x4*)(agp + j * 8 + 4);
      f16x8 t;
      t[0] = (_Float16)lo[0]; t[1] = (_Float16)lo[1];
      t[2] = (_Float16)lo[2]; t[3] = (_Float16)lo[3];
      t[4] = (_Float16)hi[0]; t[5] = (_Float16)hi[1];
      t[6] = (_Float16)hi[2]; t[7] = (_Float16)hi[3];
      *(f16x8*)(ldsA + am * 512 + ((kcg ^ am) << 4)) = t;
    }
  }
  __syncthreads();   // ldsA visible to all waves

  // ---- K-loop: 16 slices of K=16, W fragments direct from global/L2 ----
  // Wave's fragment base chunk: (mat*2+kh)*256 + cg*64 + nl; +nt*32 per
  // accumulator tile; +1024 chunks per kk2. Coalesced 2x512B segments.
  {
    const _Float16* wfrag =
        Wh2 + (size_t)((mat * 2 + kh) * 256 + cg * 64 + nl) * 8;
    for (int kk2 = 0; kk2 < 16; ++kk2) {
      f16x8 afr;
      {
        const int kcg = kk2 * 2 + kh;
        afr = *(const f16x8*)(ldsA + nl * 512 + ((kcg ^ nl) << 4));
      }
      f16x8 b0 = *(const f16x8*)(wfrag);
      f16x8 b1 = *(const f16x8*)(wfrag + 32 * 8);
      acc[0] = __builtin_amdgcn_mfma_f32_32x32x16_f16(afr, b0, acc[0], 0, 0, 0);
      acc[1] = __builtin_amdgcn_mfma_f32_32x32x16_f16(afr, b1, acc[1], 0, 0, 0);
      wfrag += SLICE_EL;
    }
  }
  __syncthreads();   // all waves done with ldsA before epilogue reuse

  // ---- epilogue: activations into 32 KiB LDS; mat0 waves write .x (byte
  // offset 0), mat1 waves write .f (byte offset 2) of each XF slot ----
  if (mat == 0) {
    const float b0 = bin[cg * 64 + nl], b1 = bin[cg * 64 + 32 + nl];
#pragma unroll
    for (int nt = 0; nt < 2; ++nt) {
      const int col = cg * 64 + nt * 32 + nl;
#pragma unroll
      for (int reg = 0; reg < 16; ++reg) {
        const int rloc = (reg & 3) + 8 * (reg >> 2) + 4 * kh;  // 0..31
        const float zx = acc[nt][reg] + (nt ? b1 : b0);
        *(_Float16*)(smem + ((size_t)rloc * D_ + col) * 4) =
            (_Float16)fast_tanh(zx);
      }
    }
  } else {
    const float b0 = bfv[cg * 64 + nl], b1 = bfv[cg * 64 + 32 + nl];
    float madd[16];
#pragma unroll
    for (int reg = 0; reg < 16; ++reg) {
      const int rl = (reg & 3) + 8 * (reg >> 2) + 4 * kh;
      madd[reg] = 10000.f * mask[row0 + rl];
    }
#pragma unroll
    for (int nt = 0; nt < 2; ++nt) {
      const int col = cg * 64 + nt * 32 + nl;
#pragma unroll
      for (int reg = 0; reg < 16; ++reg) {
        const int rloc = (reg & 3) + 8 * (reg >> 2) + 4 * kh;  // 0..31
        const float zf = acc[nt][reg] + (nt ? b1 : b0) + madd[reg];
        *(_Float16*)(smem + ((size_t)rloc * D_ + col) * 4 + 2) =
            (_Float16)fast_sigmoid(zf);
      }
    }
  }
  __syncthreads();

  // ---- local scan: 32 timesteps in place (XF -> HP2), threads 0..255 ----
  float hrun = 0.f, Prun = 1.f;
  if (tid < D_) {
    const int d = tid;
#pragma unroll 8
    for (int t = 0; t < 32; ++t) {
      char* slot = smem + ((size_t)t * D_ + d) * 4;
      const XF v = *(const XF*)slot;
      const float f = (float)v.f;
      const float a = 1.f - f;
      hrun = f * (float)v.x + a * hrun;
      Prun *= a;
      HP2 o;
      o.h = (_Float16)hrun;
      o.p = (_Float16)Prun;
      *(HP2*)slot = o;
    }
  }
  __syncthreads();

  // ---- bulk-coalesced b128 store of the 32-row HP stage (32 KiB) ----
#pragma unroll
  for (int j = 0; j < 4; ++j) {
    const int c = j * 512 + tid;              // 16B chunk id in [0,2048)
    u32x4 vv = *(const u32x4*)(smem + (size_t)c * 16);
    *(u32x4*)(HPout + (size_t)g * 8192 + (size_t)c * 4) = vv;
  }

  if (tid < D_) {
    Ap[(size_t)g * D_ + tid] = Prun;
    Hp[(size_t)g * D_ + tid] = hrun;
  }
}

// ---- K2: chunk carries, computed ONCE. 8 blocks x 256 thr ----------------
__global__ __launch_bounds__(256) void scan_mid(const float* __restrict__ Ap,
                                                const float* __restrict__ Hp,
                                                float* __restrict__ hs) {
  const int b = blockIdx.x, d = threadIdx.x;
  float h = 0.f;
#pragma unroll 8
  for (int c = 0; c < NCH; ++c) {
    const size_t i = ((size_t)(b * NCH + c)) * D_ + d;
    hs[i] = h;                         // carry INTO chunk c
    h = Hp[i] + Ap[i] * h;
  }
}

// ---- K3: h = h_local + P * h_start, pure streaming ------------------------
__global__ __launch_bounds__(256) void final_k(const unsigned int* __restrict__ HP,
                                               const float* __restrict__ hs,
                                               float* __restrict__ out) {
  const int g = blockIdx.x;
  const int wv = threadIdx.x >> 6;
  const int d0 = (threadIdx.x & 63) * 4;
  const f32x4 h0 = *(const f32x4*)(hs + (size_t)g * D_ + d0);
#pragma unroll 4
  for (int tt = 0; tt < 8; ++tt) {
    const int t = wv * 8 + tt;
    const size_t idx = ((size_t)g * CHUNK + t) * D_ + d0;
    u32x4 u = *(const u32x4*)(HP + idx);
    f32x4 o;
#pragma unroll
    for (int i = 0; i < 4; ++i) {
      UHP q; q.u = u[i];
      o[i] = (float)q.hp.h + (float)q.hp.p * h0[i];
    }
    *(f32x4*)(out + idx) = o;
  }
}

// ---------------------------------------------------------------------------
extern "C" void kernel_launch(void* const* d_in, const int* in_sizes, int n_in,
                              void* d_out, int out_size, void* d_ws, size_t ws_size,
                              hipStream_t stream) {
  const float* inputs = (const float*)d_in[0];
  const float* mask   = (const float*)d_in[1];
  const float* W_in   = (const float*)d_in[2];
  const float* b_in   = (const float*)d_in[3];
  const float* W_f    = (const float*)d_in[4];
  const float* b_f    = (const float*)d_in[5];
  float* out = (float*)d_out;
  char* ws = (char*)d_ws;

  constexpr size_t HPSZ = (size_t)M_ * D_ * 4;                    // 32 MiB
  constexpr size_t WSZ  = (size_t)2 * 256 * 256 * 2;              // 256 KiB
  constexpr size_t SUM  = (size_t)NBLK * D_ * sizeof(float);      // 1 MiB

  unsigned int* HPb = (unsigned int*)ws;
  _Float16* Wh2 = (_Float16*)(ws + HPSZ);
  float* Ap = (float*)(ws + HPSZ + WSZ);
  float* Hp = (float*)(ws + HPSZ + WSZ + SUM);
  float* hs = (float*)(ws + HPSZ + WSZ + 2 * SUM);

  wconv<<<64, 256, 0, stream>>>(W_in, W_f, Wh2);
  gemm_hp<<<NBLK, 512, 0, stream>>>(inputs, Wh2, b_in, b_f, mask, HPb, Ap, Hp);
  scan_mid<<<B_, 256, 0, stream>>>(Ap, Hp, hs);
  final_k<<<NBLK, 256, 0, stream>>>(HPb, hs, out);
}